// Round 3
// baseline (176.488 us; speedup 1.0000x reference)
//
#include <hip/hip_runtime.h>

// PAB3D on MI355X (gfx950).  B=2, C=P=64, H=W=D=16, N=4096.
// Pipeline:
//  k_prep_w    : cast/transpose weights to bf16 MFMA A-layout [k27][co][ci]
//  k_xt<0>     : x [b][c][n] f32 -> xT [b][n][c] bf16 (LDS transpose)
//  k_conv11    : top+center 1x1x1 convs fused -> T-layout bf16 [b][n][p]
//  k_conv<27,2>: bottom 3x3x3 conv -> bf16 [b][c][n]
//  k_pass1     : S=cen^T@top tiles (MFMA), per-64x64-tile (max, sum exp), 4x4 tiles/block
//  k_reduce    : global (M, 1/Z) per batch
//  k_pass2     : recompute S tiles, P=exp(S-M), LDS-transpose, P@bottom^T
//                -> invZ-scaled f32 partials over 8 m-chunks
//  k_xt<1>     : yT = bf16(x + sum_mc partial)   (fused partial reduce)
//  k_conv<27,1>: out conv -> d_out f32

typedef __attribute__((ext_vector_type(8))) short bf16x8;
typedef __attribute__((ext_vector_type(4))) short short4v;
typedef __attribute__((ext_vector_type(4))) float f32x4;

#define DEVI static __device__ __forceinline__

DEVI f32x4 MFMA16(bf16x8 a, bf16x8 b, f32x4 c) {
  return __builtin_amdgcn_mfma_f32_16x16x32_bf16(a, b, c, 0, 0, 0);
}
DEVI f32x4 zero4() { return (f32x4){0.f, 0.f, 0.f, 0.f}; }

DEVI unsigned short f2bf(float f) {  // RNE float->bf16
  unsigned u = __float_as_uint(f);
  return (unsigned short)((u + 0x7fffu + ((u >> 16) & 1u)) >> 16);
}

// ---------------- weight prep ----------------
__global__ void k_prep_w(const float* __restrict__ tw, const float* __restrict__ cw,
                         const float* __restrict__ bw, const float* __restrict__ ow,
                         unsigned short* __restrict__ wkTop, unsigned short* __restrict__ wkCen,
                         unsigned short* __restrict__ wkBot, unsigned short* __restrict__ wkOut) {
  int t = blockIdx.x * 256 + threadIdx.x;
  if (t < 4096) {
    wkTop[t] = f2bf(tw[t]);
    wkCen[t] = f2bf(cw[t]);
  }
  if (t < 110592) {  // src [co][ci][k27] -> dst [k27][co][ci]
    int k = t % 27;
    int ci = (t / 27) & 63;
    int co = t / (27 * 64);
    int dst = (k * 64 + co) * 64 + ci;
    wkBot[dst] = f2bf(bw[t]);
    wkOut[dst] = f2bf(ow[t]);
  }
}

// ---------------- transpose/cast x (ADD_SP: + partial-summed sp, buggy reshape) ----------------
template <int ADD_SP>
__global__ void k_xt(const float* __restrict__ x, const float* __restrict__ part,
                     unsigned short* __restrict__ xT) {
  __shared__ float tile[64][65];
  int bx = blockIdx.x;
  int b = bx >> 6;
  int n0 = (bx & 63) << 6;
  int t = threadIdx.x;
  {
    int nl = t & 63, cq = t >> 6;
    const float* xb = x + (size_t)b * 262144;
    int nt6 = n0 >> 6;
#pragma unroll
    for (int j = 0; j < 16; j++) {
      int c = cq * 16 + j;
      float v = xb[(size_t)c * 4096 + n0 + nl];
      if (ADD_SP) {
        // sp flat [b][nA][cA]; here nA = c*64 + nt6 (fixed), cA = nl (coalesced)
        const float* pp = part + ((size_t)((b * 64 + c) * 8)) * 4096 + nt6 * 64 + nl;
        float s = 0.f;
#pragma unroll
        for (int mcq = 0; mcq < 8; mcq++) s += pp[(size_t)mcq * 4096];
        v += s;
      }
      tile[c][nl] = v;
    }
  }
  __syncthreads();
  {
    int n = t >> 2, c0 = (t & 3) << 4;
    bf16x8 o0, o1;
#pragma unroll
    for (int j = 0; j < 8; j++) {
      o0[j] = (short)f2bf(tile[c0 + j][n]);
      o1[j] = (short)f2bf(tile[c0 + 8 + j][n]);
    }
    unsigned short* dst = xT + ((size_t)(b * 4096 + n0 + n)) * 64 + c0;
    *(bf16x8*)(dst) = o0;
    *(bf16x8*)(dst + 8) = o1;
  }
}

// ---------------- fused top+center 1x1x1 convs ----------------
__global__ void k_conv11(const unsigned short* __restrict__ wkT, const unsigned short* __restrict__ wkC,
                         const unsigned short* __restrict__ xTb,
                         const float* __restrict__ tbias, const float* __restrict__ cbias,
                         unsigned short* __restrict__ topT, unsigned short* __restrict__ cenT) {
  int bx = blockIdx.x;
  int b = bx >> 8;
  int rest = bx & 255;
  int nt = rest >> 1, ch = rest & 1;
  int t = threadIdx.x;
  int lane = t & 63, wid = t >> 6;
  int col = lane & 15, kg = lane >> 4;
  int co0 = ch * 32 + (wid >> 1) * 16;
  int n0c = nt * 32 + (wid & 1) * 16 + col;
  const unsigned short* xb = xTb + (size_t)b * 262144;

  f32x4 aT[2], aC[2];
#pragma unroll
  for (int kc = 0; kc < 2; kc++) {
    aT[kc] = zero4();
    aC[kc] = zero4();
  }
#pragma unroll
  for (int kc = 0; kc < 2; kc++) {
    bf16x8 bv = *(const bf16x8*)(xb + (size_t)n0c * 64 + kc * 32 + kg * 8);
    bf16x8 avT = *(const bf16x8*)(wkT + ((size_t)(co0 + col) * 64 + kc * 32 + kg * 8));
    bf16x8 avC = *(const bf16x8*)(wkC + ((size_t)(co0 + col) * 64 + kc * 32 + kg * 8));
    aT[kc] = MFMA16(avT, bv, aT[kc]);
    aC[kc] = MFMA16(avC, bv, aC[kc]);
  }
  short4v sT, sC;
#pragma unroll
  for (int r = 0; r < 4; r++) {
    float bvT = tbias[co0 + kg * 4 + r];
    float bvC = cbias[co0 + kg * 4 + r];
    sT[r] = (short)f2bf(aT[0][r] + aT[1][r] + bvT);
    sC[r] = (short)f2bf(aC[0][r] + aC[1][r] + bvC);
  }
  size_t o = (size_t)(b * 4096 + n0c) * 64 + co0 + kg * 4;
  *(short4v*)(topT + o) = sT;
  *(short4v*)(cenT + o) = sC;
}

// ---------------- 3x3x3 conv as 27 shifted pointwise GEMMs ----------------
// OMODE 2: bf16 [b][co][n]; OMODE 1: f32 [b][co][n]
template <int NK, int OMODE>
__global__ void k_conv(const unsigned short* __restrict__ wk,
                       const unsigned short* __restrict__ xTb,
                       const float* __restrict__ bias,
                       float* __restrict__ outF, unsigned short* __restrict__ outH) {
  int bx = blockIdx.x;
  int b = bx >> 8;
  int rest = bx & 255;
  int nt = rest >> 1, ch = rest & 1;
  int t = threadIdx.x;
  int lane = t & 63, wid = t >> 6;
  int col = lane & 15, kg = lane >> 4;
  int co0 = ch * 32 + (wid >> 1) * 16;
  int n0c = nt * 32 + (wid & 1) * 16 + col;
  const unsigned short* xb = xTb + (size_t)b * 262144;

  int h0 = n0c >> 8, w0 = (n0c >> 4) & 15, dd0 = n0c & 15;

  f32x4 acc[2];
  acc[0] = zero4();
  acc[1] = zero4();
#pragma unroll
  for (int k = 0; k < NK; k++) {
    const int dh = (NK == 1) ? 0 : (k / 9 - 1);
    const int dw = (NK == 1) ? 0 : ((k / 3) % 3 - 1);
    const int dz = (NK == 1) ? 0 : (k % 3 - 1);
    bool v0 = ((unsigned)(h0 + dh) < 16u) & ((unsigned)(w0 + dw) < 16u) & ((unsigned)(dd0 + dz) < 16u);
    int np0 = v0 ? (n0c + dh * 256 + dw * 16 + dz) : n0c;
#pragma unroll
    for (int kc = 0; kc < 2; kc++) {
      bf16x8 av = *(const bf16x8*)(wk + ((size_t)(k * 64 + co0 + col) * 64 + kc * 32 + kg * 8));
      bf16x8 bv = *(const bf16x8*)(xb + (size_t)np0 * 64 + kc * 32 + kg * 8);
      if (!v0) bv = (bf16x8){0, 0, 0, 0, 0, 0, 0, 0};
      acc[kc] = MFMA16(av, bv, acc[kc]);
    }
  }
#pragma unroll
  for (int r = 0; r < 4; r++) {
    int co = co0 + kg * 4 + r;
    float v = acc[0][r] + acc[1][r] + bias[co];
    if (OMODE == 2)
      outH[(size_t)(b * 64 + co) * 4096 + n0c] = f2bf(v);
    else
      outF[(size_t)(b * 64 + co) * 4096 + n0c] = v;
  }
}

// ---------------- pass 1: per-tile softmax stats over S = cen^T @ top ----------------
// grid = B x 64 ntiles x 16 mgroups; each block: 64 n-rows x 256 m-cols (4 tiles of 64)
__global__ void k_pass1(const unsigned short* __restrict__ cenT,
                        const unsigned short* __restrict__ topT,
                        float* __restrict__ stats) {
  int bx = blockIdx.x;
  int b = bx >> 10;
  int nt = (bx >> 4) & 63;
  int mg = bx & 15;
  int t = threadIdx.x;
  int lane = t & 63, wid = t >> 6;
  int col = lane & 15, kg = lane >> 4;
  const unsigned short* cb = cenT + (size_t)b * 262144;
  const unsigned short* tb = topT + (size_t)b * 262144;
  int n0 = nt * 64 + wid * 16;
  bf16x8 a0 = *(const bf16x8*)(cb + (size_t)(n0 + col) * 64 + kg * 8);
  bf16x8 a1 = *(const bf16x8*)(cb + (size_t)(n0 + col) * 64 + 32 + kg * 8);
  f32x4 acc[4][4];
#pragma unroll
  for (int mt = 0; mt < 4; mt++) {
    int m0 = mg * 256 + mt * 64;
#pragma unroll
    for (int ms = 0; ms < 4; ms++) {
      bf16x8 b0 = *(const bf16x8*)(tb + (size_t)(m0 + ms * 16 + col) * 64 + kg * 8);
      bf16x8 b1 = *(const bf16x8*)(tb + (size_t)(m0 + ms * 16 + col) * 64 + 32 + kg * 8);
      f32x4 a = MFMA16(a0, b0, zero4());
      acc[mt][ms] = MFMA16(a1, b1, a);
    }
  }
  __shared__ float wm[4][4], wsum[4][4];
#pragma unroll
  for (int mt = 0; mt < 4; mt++) {
    float mx = -1e30f;
#pragma unroll
    for (int ms = 0; ms < 4; ms++)
#pragma unroll
      for (int r = 0; r < 4; r++) mx = fmaxf(mx, acc[mt][ms][r]);
#pragma unroll
    for (int off = 32; off; off >>= 1) mx = fmaxf(mx, __shfl_xor(mx, off));
    if (lane == 0) wm[mt][wid] = mx;
  }
  __syncthreads();
#pragma unroll
  for (int mt = 0; mt < 4; mt++) {
    float bm = fmaxf(fmaxf(wm[mt][0], wm[mt][1]), fmaxf(wm[mt][2], wm[mt][3]));
    float s = 0.f;
#pragma unroll
    for (int ms = 0; ms < 4; ms++)
#pragma unroll
      for (int r = 0; r < 4; r++) s += __expf(acc[mt][ms][r] - bm);
#pragma unroll
    for (int off = 32; off; off >>= 1) s += __shfl_xor(s, off);
    if (lane == 0) wsum[mt][wid] = s;
  }
  __syncthreads();
  if (t < 4) {
    int mt = t;
    float bm = fmaxf(fmaxf(wm[mt][0], wm[mt][1]), fmaxf(wm[mt][2], wm[mt][3]));
    float s = wsum[mt][0] + wsum[mt][1] + wsum[mt][2] + wsum[mt][3];
    float* o = stats + (size_t)(b * 4096 + nt * 64 + mg * 4 + mt) * 2;
    o[0] = bm;
    o[1] = s;
  }
}

// ---------------- global (M, 1/Z) per batch ----------------
__global__ void k_reduce(const float* __restrict__ stats, float* __restrict__ MZ) {
  int b = blockIdx.x;
  int t = threadIdx.x;
  const float* st = stats + (size_t)b * 8192;
  float mx = -1e30f;
  for (int i = t; i < 4096; i += 256) mx = fmaxf(mx, st[2 * i]);
#pragma unroll
  for (int off = 32; off; off >>= 1) mx = fmaxf(mx, __shfl_xor(mx, off));
  __shared__ float red[4];
  if ((t & 63) == 0) red[t >> 6] = mx;
  __syncthreads();
  float M = fmaxf(fmaxf(red[0], red[1]), fmaxf(red[2], red[3]));
  float z = 0.f;
  for (int i = t; i < 4096; i += 256) z += st[2 * i + 1] * __expf(st[2 * i] - M);
#pragma unroll
  for (int off = 32; off; off >>= 1) z += __shfl_xor(z, off);
  __syncthreads();
  if ((t & 63) == 0) red[t >> 6] = z;
  __syncthreads();
  if (t == 0) {
    float Z = red[0] + red[1] + red[2] + red[3];
    MZ[b * 2] = M;
    MZ[b * 2 + 1] = 1.0f / Z;
  }
}

// ---------------- pass 2: partial O over m-chunks ----------------
// grid = B x 64 ntiles x 8 mchunks; wave w owns rows nt*64+w*16, m in [mc*512, +512)
__global__ void k_pass2(const unsigned short* __restrict__ cenT,
                        const unsigned short* __restrict__ topT,
                        const unsigned short* __restrict__ botS,
                        const float* __restrict__ MZ,
                        float* __restrict__ part) {
  __shared__ __align__(16) unsigned short plds[2][4][1024];  // dbuf x wave x 16x64 P tile
  int bx = blockIdx.x;
  int b = bx >> 9;
  int nt = (bx >> 3) & 63;
  int mc = bx & 7;
  int t = threadIdx.x;
  int lane = t & 63, wid = t >> 6;
  int col = lane & 15, kg = lane >> 4;
  const unsigned short* cb = cenT + (size_t)b * 262144;
  const unsigned short* tb = topT + (size_t)b * 262144;
  const unsigned short* bb = botS + (size_t)b * 262144;
  float M = MZ[b * 2], invZ = MZ[b * 2 + 1];
  int n0 = nt * 64 + wid * 16;

  bf16x8 aS0 = *(const bf16x8*)(cb + (size_t)(n0 + col) * 64 + kg * 8);
  bf16x8 aS1 = *(const bf16x8*)(cb + (size_t)(n0 + col) * 64 + 32 + kg * 8);

  f32x4 accO[4];
#pragma unroll
  for (int ct = 0; ct < 4; ct++) accO[ct] = zero4();

#pragma unroll
  for (int j = 0; j < 8; j++) {
    int m0 = mc * 512 + j * 64;
    f32x4 accS[4];
#pragma unroll
    for (int mt = 0; mt < 4; mt++) {
      bf16x8 b0 = *(const bf16x8*)(tb + (size_t)(m0 + mt * 16 + col) * 64 + kg * 8);
      bf16x8 b1 = *(const bf16x8*)(tb + (size_t)(m0 + mt * 16 + col) * 64 + 32 + kg * 8);
      f32x4 a = MFMA16(aS0, b0, zero4());
      accS[mt] = MFMA16(aS1, b1, a);
    }
    unsigned short* pw = &plds[j & 1][wid][0];
#pragma unroll
    for (int mt = 0; mt < 4; mt++) {
#pragma unroll
      for (int r = 0; r < 4; r++) {
        int nrow = kg * 4 + r;
        int m = mt * 16 + col;
        pw[nrow * 64 + (m ^ ((nrow & 7) << 3))] = f2bf(__expf(accS[mt][r] - M));
      }
    }
    // per-wave private LDS tile: intra-wave lgkmcnt ordering suffices, no barrier
#pragma unroll
    for (int kc = 0; kc < 2; kc++) {
      bf16x8 pa = *(const bf16x8*)&pw[col * 64 + ((kc * 32 + kg * 8) ^ ((col & 7) << 3))];
#pragma unroll
      for (int ct = 0; ct < 4; ct++) {
        bf16x8 bv = *(const bf16x8*)(bb + (size_t)(ct * 16 + col) * 4096 + m0 + kc * 32 + kg * 8);
        accO[ct] = MFMA16(pa, bv, accO[ct]);
      }
    }
  }
  float* po = part + ((size_t)((b * 64 + nt) * 8 + mc)) * 4096;
#pragma unroll
  for (int ct = 0; ct < 4; ct++)
#pragma unroll
    for (int r = 0; r < 4; r++)
      po[(wid * 16 + kg * 4 + r) * 64 + ct * 16 + col] = accO[ct][r] * invZ;
}

// ---------------- host ----------------
extern "C" void kernel_launch(void* const* d_in, const int* in_sizes, int n_in,
                              void* d_out, int out_size, void* d_ws, size_t ws_size,
                              hipStream_t stream) {
  const float* x = (const float*)d_in[0];
  const float* tw = (const float*)d_in[1];
  const float* tb = (const float*)d_in[2];
  const float* cw = (const float*)d_in[3];
  const float* cbb = (const float*)d_in[4];
  const float* bw = (const float*)d_in[5];
  const float* bb = (const float*)d_in[6];
  const float* ow = (const float*)d_in[7];
  const float* ob = (const float*)d_in[8];
  float* out = (float*)d_out;
  char* ws = (char*)d_ws;

  unsigned short* wkTop = (unsigned short*)(ws + 0);        // 8 KB
  unsigned short* wkCen = (unsigned short*)(ws + 8192);     // 8 KB
  unsigned short* wkBot = (unsigned short*)(ws + 16384);    // 216 KB
  unsigned short* wkOut = (unsigned short*)(ws + 237568);   // 216 KB
  unsigned short* xT = (unsigned short*)(ws + 458752);      // 1 MB
  unsigned short* topT = (unsigned short*)(ws + 1507328);   // 1 MB
  unsigned short* cenT = (unsigned short*)(ws + 2555904);   // 1 MB
  unsigned short* botS = (unsigned short*)(ws + 3604480);   // 1 MB
  unsigned short* yT = (unsigned short*)(ws + 4653056);     // 1 MB
  float* part = (float*)(ws + 5701632);                     // 16 MB
  float* stats = (float*)(ws + 22478848);                   // 64 KB
  float* MZ = (float*)(ws + 22544384);                      // 16 B

  k_prep_w<<<432, 256, 0, stream>>>(tw, cw, bw, ow, wkTop, wkCen, wkBot, wkOut);
  k_xt<0><<<128, 256, 0, stream>>>(x, nullptr, xT);
  k_conv11<<<512, 256, 0, stream>>>(wkTop, wkCen, xT, tb, cbb, topT, cenT);
  k_conv<27, 2><<<512, 256, 0, stream>>>(wkBot, xT, bb, nullptr, botS);
  k_pass1<<<2048, 256, 0, stream>>>(cenT, topT, stats);
  k_reduce<<<2, 256, 0, stream>>>(stats, MZ);
  k_pass2<<<1024, 256, 0, stream>>>(cenT, topT, botS, MZ, part);
  k_xt<1><<<128, 256, 0, stream>>>(x, part, yT);
  k_conv<27, 1><<<512, 256, 0, stream>>>(wkOut, yT, ob, out, nullptr);
}

// Round 4
// 131.036 us; speedup vs baseline: 1.3469x; 1.3469x over previous
//
#include <hip/hip_runtime.h>

// PAB3D on MI355X (gfx950).  B=2, C=P=64, H=W=D=16, N=4096.
// R4: pass1/pass2 rebuilt around block-shared LDS staging (global_load_lds,
// dbuf, XOR-swizzled) to kill the scattered 16-line B-frag global loads that
// R1/R3 showed to be the invariant bottleneck (~64us with all pipes idle).

typedef __attribute__((ext_vector_type(8))) short bf16x8;
typedef __attribute__((ext_vector_type(4))) short short4v;
typedef __attribute__((ext_vector_type(4))) float f32x4;

#define DEVI static __device__ __forceinline__

DEVI f32x4 MFMA16(bf16x8 a, bf16x8 b, f32x4 c) {
  return __builtin_amdgcn_mfma_f32_16x16x32_bf16(a, b, c, 0, 0, 0);
}
DEVI f32x4 zero4() { return (f32x4){0.f, 0.f, 0.f, 0.f}; }

DEVI unsigned short f2bf(float f) {  // RNE float->bf16
  unsigned u = __float_as_uint(f);
  return (unsigned short)((u + 0x7fffu + ((u >> 16) & 1u)) >> 16);
}
DEVI float bf2f(unsigned short u) { return __uint_as_float((unsigned)u << 16); }

// async global->LDS, 16B per lane; lds dest must be wave-uniform base (HW adds lane*16)
DEVI void gll16(const unsigned short* g, unsigned short* l) {
  __builtin_amdgcn_global_load_lds(
      (const __attribute__((address_space(1))) void*)g,
      (__attribute__((address_space(3))) void*)l, 16, 0, 0);
}

// ---------------- weight prep ----------------
__global__ void k_prep_w(const float* __restrict__ tw, const float* __restrict__ cw,
                         const float* __restrict__ bw, const float* __restrict__ ow,
                         unsigned short* __restrict__ wkTop, unsigned short* __restrict__ wkCen,
                         unsigned short* __restrict__ wkBot, unsigned short* __restrict__ wkOut) {
  int t = blockIdx.x * 256 + threadIdx.x;
  if (t < 4096) {
    wkTop[t] = f2bf(tw[t]);
    wkCen[t] = f2bf(cw[t]);
  }
  if (t < 110592) {  // src [co][ci][k27] -> dst [k27][co][ci]
    int k = t % 27;
    int ci = (t / 27) & 63;
    int co = t / (27 * 64);
    int dst = (k * 64 + co) * 64 + ci;
    wkBot[dst] = f2bf(bw[t]);
    wkOut[dst] = f2bf(ow[t]);
  }
}

// ---------------- transpose/cast x (ADD_SP: + bf16 partial sum, buggy reshape) ----------------
template <int ADD_SP>
__global__ void k_xt(const float* __restrict__ x, const unsigned short* __restrict__ part,
                     unsigned short* __restrict__ xT) {
  __shared__ float tile[64][65];
  int bx = blockIdx.x;
  int b = bx >> 6;
  int n0 = (bx & 63) << 6;
  int t = threadIdx.x;
  {
    int nl = t & 63, cq = t >> 6;
    const float* xb = x + (size_t)b * 262144;
    int nt6 = n0 >> 6;
#pragma unroll
    for (int j = 0; j < 16; j++) {
      int c = cq * 16 + j;
      float v = xb[(size_t)c * 4096 + n0 + nl];
      if (ADD_SP) {
        // sp flat [b][nA][cA]; nA = c*64 + nt6 (fixed per j), cA = nl (coalesced)
        float s = 0.f;
#pragma unroll
        for (int mcq = 0; mcq < 8; mcq++)
          s += bf2f(part[(((size_t)(b * 8 + mcq) * 4096) + c * 64 + nt6) * 64 + nl]);
        v += s;
      }
      tile[c][nl] = v;
    }
  }
  __syncthreads();
  {
    int n = t >> 2, c0 = (t & 3) << 4;
    bf16x8 o0, o1;
#pragma unroll
    for (int j = 0; j < 8; j++) {
      o0[j] = (short)f2bf(tile[c0 + j][n]);
      o1[j] = (short)f2bf(tile[c0 + 8 + j][n]);
    }
    unsigned short* dst = xT + ((size_t)(b * 4096 + n0 + n)) * 64 + c0;
    *(bf16x8*)(dst) = o0;
    *(bf16x8*)(dst + 8) = o1;
  }
}

// ---------------- fused top+center 1x1x1 convs ----------------
__global__ void k_conv11(const unsigned short* __restrict__ wkT, const unsigned short* __restrict__ wkC,
                         const unsigned short* __restrict__ xTb,
                         const float* __restrict__ tbias, const float* __restrict__ cbias,
                         unsigned short* __restrict__ topT, unsigned short* __restrict__ cenT) {
  int bx = blockIdx.x;
  int b = bx >> 8;
  int rest = bx & 255;
  int nt = rest >> 1, ch = rest & 1;
  int t = threadIdx.x;
  int lane = t & 63, wid = t >> 6;
  int col = lane & 15, kg = lane >> 4;
  int co0 = ch * 32 + (wid >> 1) * 16;
  int n0c = nt * 32 + (wid & 1) * 16 + col;
  const unsigned short* xb = xTb + (size_t)b * 262144;

  f32x4 aT[2], aC[2];
#pragma unroll
  for (int kc = 0; kc < 2; kc++) {
    aT[kc] = zero4();
    aC[kc] = zero4();
  }
#pragma unroll
  for (int kc = 0; kc < 2; kc++) {
    bf16x8 bv = *(const bf16x8*)(xb + (size_t)n0c * 64 + kc * 32 + kg * 8);
    bf16x8 avT = *(const bf16x8*)(wkT + ((size_t)(co0 + col) * 64 + kc * 32 + kg * 8));
    bf16x8 avC = *(const bf16x8*)(wkC + ((size_t)(co0 + col) * 64 + kc * 32 + kg * 8));
    aT[kc] = MFMA16(avT, bv, aT[kc]);
    aC[kc] = MFMA16(avC, bv, aC[kc]);
  }
  short4v sT, sC;
#pragma unroll
  for (int r = 0; r < 4; r++) {
    float bvT = tbias[co0 + kg * 4 + r];
    float bvC = cbias[co0 + kg * 4 + r];
    sT[r] = (short)f2bf(aT[0][r] + aT[1][r] + bvT);
    sC[r] = (short)f2bf(aC[0][r] + aC[1][r] + bvC);
  }
  size_t o = (size_t)(b * 4096 + n0c) * 64 + co0 + kg * 4;
  *(short4v*)(topT + o) = sT;
  *(short4v*)(cenT + o) = sC;
}

// ---------------- 3x3x3 conv as 27 shifted pointwise GEMMs ----------------
// OMODE 2: bf16 [b][co][n]; OMODE 1: f32 [b][co][n]
template <int NK, int OMODE>
__global__ void k_conv(const unsigned short* __restrict__ wk,
                       const unsigned short* __restrict__ xTb,
                       const float* __restrict__ bias,
                       float* __restrict__ outF, unsigned short* __restrict__ outH) {
  int bx = blockIdx.x;
  int b = bx >> 8;
  int rest = bx & 255;
  int nt = rest >> 1, ch = rest & 1;
  int t = threadIdx.x;
  int lane = t & 63, wid = t >> 6;
  int col = lane & 15, kg = lane >> 4;
  int co0 = ch * 32 + (wid >> 1) * 16;
  int n0c = nt * 32 + (wid & 1) * 16 + col;
  const unsigned short* xb = xTb + (size_t)b * 262144;

  int h0 = n0c >> 8, w0 = (n0c >> 4) & 15, dd0 = n0c & 15;

  f32x4 acc[2];
  acc[0] = zero4();
  acc[1] = zero4();
#pragma unroll
  for (int k = 0; k < NK; k++) {
    const int dh = (NK == 1) ? 0 : (k / 9 - 1);
    const int dw = (NK == 1) ? 0 : ((k / 3) % 3 - 1);
    const int dz = (NK == 1) ? 0 : (k % 3 - 1);
    bool v0 = ((unsigned)(h0 + dh) < 16u) & ((unsigned)(w0 + dw) < 16u) & ((unsigned)(dd0 + dz) < 16u);
    int np0 = v0 ? (n0c + dh * 256 + dw * 16 + dz) : n0c;
#pragma unroll
    for (int kc = 0; kc < 2; kc++) {
      bf16x8 av = *(const bf16x8*)(wk + ((size_t)(k * 64 + co0 + col) * 64 + kc * 32 + kg * 8));
      bf16x8 bv = *(const bf16x8*)(xb + (size_t)np0 * 64 + kc * 32 + kg * 8);
      if (!v0) bv = (bf16x8){0, 0, 0, 0, 0, 0, 0, 0};
      acc[kc] = MFMA16(av, bv, acc[kc]);
    }
  }
#pragma unroll
  for (int r = 0; r < 4; r++) {
    int co = co0 + kg * 4 + r;
    float v = acc[0][r] + acc[1][r] + bias[co];
    if (OMODE == 2)
      outH[(size_t)(b * 64 + co) * 4096 + n0c] = f2bf(v);
    else
      outF[(size_t)(b * 64 + co) * 4096 + n0c] = v;
  }
}

// ---------------- pass 1: LDS-staged S stats ----------------
// grid = B x 64 ntiles(64 rows) x 8 mchunks(512); wave w owns rows nt*64+w*16.
// Per-lane online (M,S) over its 16 S-values per 64-m iter; wave-reduce at end.
__global__ __launch_bounds__(256, 4) void k_pass1(
    const unsigned short* __restrict__ cenT, const unsigned short* __restrict__ topT,
    float* __restrict__ stats) {
  __shared__ __align__(16) unsigned short topS[2][4096];
  int bx = blockIdx.x;
  int b = bx >> 9;
  int nt = (bx >> 3) & 63;
  int mc = bx & 7;
  int t = threadIdx.x;
  int lane = t & 63, w = t >> 6;
  int col = lane & 15, kg = lane >> 4;
  const unsigned short* cb = cenT + (size_t)b * 262144;
  const unsigned short* tb = topT + (size_t)b * 262144;
  int n0 = nt * 64 + w * 16;
  int mcBase = mc * 512;
  int row8 = lane >> 3, blk = lane & 7;
  int sw = blk ^ (row8 & 7);  // inverse-swizzled source 16B block

  bf16x8 aS0 = *(const bf16x8*)(cb + (size_t)(n0 + col) * 64 + kg * 8);
  bf16x8 aS1 = *(const bf16x8*)(cb + (size_t)(n0 + col) * 64 + 32 + kg * 8);

  // prologue stage j=0
#pragma unroll
  for (int q = 0; q < 2; q++) {
    int s = w * 2 + q;
    gll16(tb + (size_t)(mcBase + s * 8 + row8) * 64 + sw * 8, &topS[0][s * 512]);
  }
  __syncthreads();

  float Ml = -1e30f, Sl = 0.f;
  int swc = (col & 7) << 3;
  for (int j = 0; j < 8; j++) {
    int cur = j & 1;
    if (j < 7) {
      int m0 = mcBase + (j + 1) * 64;
#pragma unroll
      for (int q = 0; q < 2; q++) {
        int s = w * 2 + q;
        gll16(tb + (size_t)(m0 + s * 8 + row8) * 64 + sw * 8, &topS[cur ^ 1][s * 512]);
      }
    }
    f32x4 accS[4];
#pragma unroll
    for (int mt = 0; mt < 4; mt++) {
      bf16x8 b0 = *(const bf16x8*)&topS[cur][(mt * 16 + col) * 64 + ((kg * 8) ^ swc)];
      bf16x8 b1 = *(const bf16x8*)&topS[cur][(mt * 16 + col) * 64 + ((32 + kg * 8) ^ swc)];
      f32x4 a = MFMA16(aS0, b0, zero4());
      accS[mt] = MFMA16(aS1, b1, a);
    }
    float mx = -1e30f;
#pragma unroll
    for (int mt = 0; mt < 4; mt++)
#pragma unroll
      for (int r = 0; r < 4; r++) mx = fmaxf(mx, accS[mt][r]);
    float Mn = fmaxf(Ml, mx);
    float s = 0.f;
#pragma unroll
    for (int mt = 0; mt < 4; mt++)
#pragma unroll
      for (int r = 0; r < 4; r++) s += __expf(accS[mt][r] - Mn);
    Sl = Sl * __expf(Ml - Mn) + s;
    Ml = Mn;
    __syncthreads();
  }
  // wave-level (M,S) merge
#pragma unroll
  for (int off = 32; off; off >>= 1) {
    float Mo = __shfl_xor(Ml, off), So = __shfl_xor(Sl, off);
    float Mn = fmaxf(Ml, Mo);
    Sl = Sl * __expf(Ml - Mn) + So * __expf(Mo - Mn);
    Ml = Mn;
  }
  if (lane == 0) {
    float* o = stats + ((size_t)(b * 2048 + (nt * 4 + w) * 8 + mc)) * 2;
    o[0] = Ml;
    o[1] = Sl;
  }
}

// ---------------- global (M, 1/Z) per batch ----------------
__global__ void k_reduce(const float* __restrict__ stats, float* __restrict__ MZ) {
  int b = blockIdx.x;
  int t = threadIdx.x;
  const float* st = stats + (size_t)b * 4096;
  float mx = -1e30f;
  for (int i = t; i < 2048; i += 256) mx = fmaxf(mx, st[2 * i]);
#pragma unroll
  for (int off = 32; off; off >>= 1) mx = fmaxf(mx, __shfl_xor(mx, off));
  __shared__ float red[4];
  if ((t & 63) == 0) red[t >> 6] = mx;
  __syncthreads();
  float M = fmaxf(fmaxf(red[0], red[1]), fmaxf(red[2], red[3]));
  float z = 0.f;
  for (int i = t; i < 2048; i += 256) z += st[2 * i + 1] * __expf(st[2 * i] - M);
#pragma unroll
  for (int off = 32; off; off >>= 1) z += __shfl_xor(z, off);
  __syncthreads();
  if ((t & 63) == 0) red[t >> 6] = z;
  __syncthreads();
  if (t == 0) {
    float Z = red[0] + red[1] + red[2] + red[3];
    MZ[b * 2] = M;
    MZ[b * 2 + 1] = 1.0f / Z;
  }
}

// ---------------- pass 2: LDS-staged S recompute + PV, bf16 partials ----------------
// grid = B x 64 ntiles(64 rows) x 8 mchunks(512); wave w owns rows nt*64+w*16.
__global__ __launch_bounds__(256, 4) void k_pass2(
    const unsigned short* __restrict__ cenT, const unsigned short* __restrict__ topT,
    const unsigned short* __restrict__ botS, const float* __restrict__ MZ,
    unsigned short* __restrict__ part) {
  __shared__ __align__(16) unsigned short topS[2][4096];
  __shared__ __align__(16) unsigned short botL[2][4096];
  __shared__ __align__(16) unsigned short pT[4][1024];
  int bx = blockIdx.x;
  int b = bx >> 9;
  int nt = (bx >> 3) & 63;
  int mc = bx & 7;
  int t = threadIdx.x;
  int lane = t & 63, w = t >> 6;
  int col = lane & 15, kg = lane >> 4;
  const unsigned short* cb = cenT + (size_t)b * 262144;
  const unsigned short* tb = topT + (size_t)b * 262144;
  const unsigned short* bb = botS + (size_t)b * 262144;
  float M = MZ[b * 2], invZ = MZ[b * 2 + 1];
  int n0 = nt * 64 + w * 16;
  int mcBase = mc * 512;
  int row8 = lane >> 3, blk = lane & 7;
  int sw = blk ^ (row8 & 7);

  bf16x8 aS0 = *(const bf16x8*)(cb + (size_t)(n0 + col) * 64 + kg * 8);
  bf16x8 aS1 = *(const bf16x8*)(cb + (size_t)(n0 + col) * 64 + 32 + kg * 8);

  // prologue stage j=0: waves 0,1 -> top; waves 2,3 -> bot
  if (w < 2) {
#pragma unroll
    for (int q = 0; q < 4; q++) {
      int s = w * 4 + q;
      gll16(tb + (size_t)(mcBase + s * 8 + row8) * 64 + sw * 8, &topS[0][s * 512]);
    }
  } else {
#pragma unroll
    for (int q = 0; q < 4; q++) {
      int s = (w - 2) * 4 + q;
      gll16(bb + (size_t)(s * 8 + row8) * 4096 + mcBase + sw * 8, &botL[0][s * 512]);
    }
  }
  __syncthreads();

  f32x4 accO[4];
#pragma unroll
  for (int ct = 0; ct < 4; ct++) accO[ct] = zero4();
  int swc = (col & 7) << 3;
  unsigned short* pw = &pT[w][0];

  for (int j = 0; j < 8; j++) {
    int cur = j & 1;
    if (j < 7) {
      int m0 = mcBase + (j + 1) * 64;
      if (w < 2) {
#pragma unroll
        for (int q = 0; q < 4; q++) {
          int s = w * 4 + q;
          gll16(tb + (size_t)(m0 + s * 8 + row8) * 64 + sw * 8, &topS[cur ^ 1][s * 512]);
        }
      } else {
#pragma unroll
        for (int q = 0; q < 4; q++) {
          int s = (w - 2) * 4 + q;
          gll16(bb + (size_t)(s * 8 + row8) * 4096 + m0 + sw * 8, &botL[cur ^ 1][s * 512]);
        }
      }
    }
    // S tile 16n x 64m from LDS
    f32x4 accS[4];
#pragma unroll
    for (int mt = 0; mt < 4; mt++) {
      bf16x8 b0 = *(const bf16x8*)&topS[cur][(mt * 16 + col) * 64 + ((kg * 8) ^ swc)];
      bf16x8 b1 = *(const bf16x8*)&topS[cur][(mt * 16 + col) * 64 + ((32 + kg * 8) ^ swc)];
      f32x4 a = MFMA16(aS0, b0, zero4());
      accS[mt] = MFMA16(aS1, b1, a);
    }
    // P = exp(S-M) -> per-wave LDS tile (D-layout -> A-layout transpose)
#pragma unroll
    for (int mt = 0; mt < 4; mt++)
#pragma unroll
      for (int r = 0; r < 4; r++) {
        int nrow = kg * 4 + r;
        int m = mt * 16 + col;
        pw[nrow * 64 + (m ^ ((nrow & 7) << 3))] = f2bf(__expf(accS[mt][r] - M));
      }
    // PV: A = P from LDS, B = bot from LDS
#pragma unroll
    for (int kc = 0; kc < 2; kc++) {
      bf16x8 pa = *(const bf16x8*)&pw[col * 64 + ((kc * 32 + kg * 8) ^ swc)];
#pragma unroll
      for (int ct = 0; ct < 4; ct++) {
        bf16x8 bv = *(const bf16x8*)&botL[cur][(ct * 16 + col) * 64 + ((kc * 32 + kg * 8) ^ swc)];
        accO[ct] = MFMA16(pa, bv, accO[ct]);
      }
    }
    __syncthreads();
  }
  // bf16 partials: part[b][mc][n][c]
  unsigned short* po = part + (((size_t)(b * 8 + mc) * 4096 + n0) << 6);
#pragma unroll
  for (int ct = 0; ct < 4; ct++)
#pragma unroll
    for (int r = 0; r < 4; r++)
      po[(kg * 4 + r) * 64 + ct * 16 + col] = f2bf(accO[ct][r] * invZ);
}

// ---------------- host ----------------
extern "C" void kernel_launch(void* const* d_in, const int* in_sizes, int n_in,
                              void* d_out, int out_size, void* d_ws, size_t ws_size,
                              hipStream_t stream) {
  const float* x = (const float*)d_in[0];
  const float* tw = (const float*)d_in[1];
  const float* tb = (const float*)d_in[2];
  const float* cw = (const float*)d_in[3];
  const float* cbb = (const float*)d_in[4];
  const float* bw = (const float*)d_in[5];
  const float* bb = (const float*)d_in[6];
  const float* ow = (const float*)d_in[7];
  const float* ob = (const float*)d_in[8];
  float* out = (float*)d_out;
  char* ws = (char*)d_ws;

  unsigned short* wkTop = (unsigned short*)(ws + 0);        // 8 KB
  unsigned short* wkCen = (unsigned short*)(ws + 8192);     // 8 KB
  unsigned short* wkBot = (unsigned short*)(ws + 16384);    // 216 KB
  unsigned short* wkOut = (unsigned short*)(ws + 237568);   // 216 KB
  unsigned short* xT = (unsigned short*)(ws + 458752);      // 1 MB
  unsigned short* topT = (unsigned short*)(ws + 1507328);   // 1 MB
  unsigned short* cenT = (unsigned short*)(ws + 2555904);   // 1 MB
  unsigned short* botS = (unsigned short*)(ws + 3604480);   // 1 MB
  unsigned short* yT = (unsigned short*)(ws + 4653056);     // 1 MB
  unsigned short* part = (unsigned short*)(ws + 5701632);   // 8 MB bf16 [2][8][4096][64]
  float* stats = (float*)(ws + 14090240);                   // 32 KB
  float* MZ = (float*)(ws + 14123008);                      // 16 B

  k_prep_w<<<432, 256, 0, stream>>>(tw, cw, bw, ow, wkTop, wkCen, wkBot, wkOut);
  k_xt<0><<<128, 256, 0, stream>>>(x, nullptr, xT);
  k_conv11<<<512, 256, 0, stream>>>(wkTop, wkCen, xT, tb, cbb, topT, cenT);
  k_conv<27, 2><<<512, 256, 0, stream>>>(wkBot, xT, bb, nullptr, botS);
  k_pass1<<<1024, 256, 0, stream>>>(cenT, topT, stats);
  k_reduce<<<2, 256, 0, stream>>>(stats, MZ);
  k_pass2<<<1024, 256, 0, stream>>>(cenT, topT, botS, MZ, part);
  k_xt<1><<<128, 256, 0, stream>>>(x, part, yT);
  k_conv<27, 1><<<512, 256, 0, stream>>>(wkOut, yT, ob, out, nullptr);
}

// Round 7
// 86.195 us; speedup vs baseline: 2.0476x; 1.5202x over previous
//
#include <hip/hip_runtime.h>

// PAB3D on MI355X (gfx950).  B=2, C=P=64, H=W=D=16, N=4096.
// R7 = R6 with the pass2 B-tile partial-store race fixed (stray +4032 offset
// pushed tile-B rows into other blocks' part regions -> replay nondeterminism).
// R5 design: no pass1/reduce (S bounded, exp(S) safe in f32, softmax shift-
// invariant). Pass2: P=exp2(S') with log2e folded into cen, O-partials (bf16)
// + per-block Z-partials; k_xt1 reduces Z and applies 1/Z. 5 launches.

typedef __attribute__((ext_vector_type(8))) short bf16x8;
typedef __attribute__((ext_vector_type(4))) short short4v;
typedef __attribute__((ext_vector_type(4))) float f32x4;

#define DEVI static __device__ __forceinline__

DEVI f32x4 MFMA16(bf16x8 a, bf16x8 b, f32x4 c) {
  return __builtin_amdgcn_mfma_f32_16x16x32_bf16(a, b, c, 0, 0, 0);
}
DEVI f32x4 zero4() { return (f32x4){0.f, 0.f, 0.f, 0.f}; }

DEVI unsigned short f2bf(float f) {  // RNE float->bf16
  unsigned u = __float_as_uint(f);
  return (unsigned short)((u + 0x7fffu + ((u >> 16) & 1u)) >> 16);
}
DEVI float bf2f(unsigned short u) { return __uint_as_float((unsigned)u << 16); }
DEVI float fexp2(float x) { return __builtin_amdgcn_exp2f(x); }

// async global->LDS, 16B per lane; lds dest is wave-uniform base (HW adds lane*16)
DEVI void gll16(const unsigned short* g, unsigned short* l) {
  __builtin_amdgcn_global_load_lds(
      (const __attribute__((address_space(1))) void*)g,
      (__attribute__((address_space(3))) void*)l, 16, 0, 0);
}

// ---------------- fused: weight prep (bx<432) + x transpose/cast (bx>=432) ----------------
__global__ void k_prep(const float* __restrict__ tw, const float* __restrict__ cw,
                       const float* __restrict__ bw, const float* __restrict__ ow,
                       const float* __restrict__ x,
                       unsigned short* __restrict__ wkTop, unsigned short* __restrict__ wkCen,
                       unsigned short* __restrict__ wkBot, unsigned short* __restrict__ wkOut,
                       unsigned short* __restrict__ xT) {
  __shared__ float tile[64][65];
  int bx = blockIdx.x;
  int tid = threadIdx.x;
  if (bx < 432) {
    int t = bx * 256 + tid;
    if (t < 4096) {
      wkTop[t] = f2bf(tw[t]);
      wkCen[t] = f2bf(cw[t]);
    }
    // src [co][ci][k27] -> dst [k27][co][ci]
    int k = t % 27;
    int ci = (t / 27) & 63;
    int co = t / (27 * 64);
    int dst = (k * 64 + co) * 64 + ci;
    wkBot[dst] = f2bf(bw[t]);
    wkOut[dst] = f2bf(ow[t]);
    return;
  }
  int bx2 = bx - 432;
  int b = bx2 >> 6;
  int n0 = (bx2 & 63) << 6;
  {
    int nl = tid & 63, cq = tid >> 6;
    const float* xb = x + (size_t)b * 262144;
#pragma unroll
    for (int j = 0; j < 16; j++) {
      int c = cq * 16 + j;
      tile[c][nl] = xb[(size_t)c * 4096 + n0 + nl];
    }
  }
  __syncthreads();
  {
    int n = tid >> 2, c0 = (tid & 3) << 4;
    bf16x8 o0, o1;
#pragma unroll
    for (int j = 0; j < 8; j++) {
      o0[j] = (short)f2bf(tile[c0 + j][n]);
      o1[j] = (short)f2bf(tile[c0 + 8 + j][n]);
    }
    unsigned short* dst = xT + ((size_t)(b * 4096 + n0 + n)) * 64 + c0;
    *(bf16x8*)(dst) = o0;
    *(bf16x8*)(dst + 8) = o1;
  }
}

// ---------------- fused: top+center 1x1x1 (bx<512) + bottom 3x3x3 (bx>=512) ----------------
__global__ void k_convA(const unsigned short* __restrict__ wkT, const unsigned short* __restrict__ wkC,
                        const unsigned short* __restrict__ wkB,
                        const unsigned short* __restrict__ xTb,
                        const float* __restrict__ tbias, const float* __restrict__ cbias,
                        const float* __restrict__ bbias,
                        unsigned short* __restrict__ topT, unsigned short* __restrict__ cenT,
                        unsigned short* __restrict__ botS) {
  int bx0 = blockIdx.x;
  int t = threadIdx.x;
  int lane = t & 63, wid = t >> 6;
  int col = lane & 15, kg = lane >> 4;
  if (bx0 < 512) {
    int bx = bx0;
    int b = bx >> 8;
    int rest = bx & 255;
    int nt = rest >> 1, ch = rest & 1;
    int co0 = ch * 32 + (wid >> 1) * 16;
    int n0c = nt * 32 + (wid & 1) * 16 + col;
    const unsigned short* xb = xTb + (size_t)b * 262144;
    f32x4 aT[2], aC[2];
#pragma unroll
    for (int kc = 0; kc < 2; kc++) {
      aT[kc] = zero4();
      aC[kc] = zero4();
    }
#pragma unroll
    for (int kc = 0; kc < 2; kc++) {
      bf16x8 bv = *(const bf16x8*)(xb + (size_t)n0c * 64 + kc * 32 + kg * 8);
      bf16x8 avT = *(const bf16x8*)(wkT + ((size_t)(co0 + col) * 64 + kc * 32 + kg * 8));
      bf16x8 avC = *(const bf16x8*)(wkC + ((size_t)(co0 + col) * 64 + kc * 32 + kg * 8));
      aT[kc] = MFMA16(avT, bv, aT[kc]);
      aC[kc] = MFMA16(avC, bv, aC[kc]);
    }
    const float LOG2E = 1.4426950408889634f;
    short4v sT, sC;
#pragma unroll
    for (int r = 0; r < 4; r++) {
      float bvT = tbias[co0 + kg * 4 + r];
      float bvC = cbias[co0 + kg * 4 + r];
      sT[r] = (short)f2bf(aT[0][r] + aT[1][r] + bvT);
      sC[r] = (short)f2bf((aC[0][r] + aC[1][r] + bvC) * LOG2E);  // fold log2e for exp2
    }
    size_t o = (size_t)(b * 4096 + n0c) * 64 + co0 + kg * 4;
    *(short4v*)(topT + o) = sT;
    *(short4v*)(cenT + o) = sC;
    return;
  }
  // bottom 3x3x3 conv -> bf16 [b][co][n]
  int bx = bx0 - 512;
  int b = bx >> 8;
  int rest = bx & 255;
  int nt = rest >> 1, ch = rest & 1;
  int co0 = ch * 32 + (wid >> 1) * 16;
  int n0c = nt * 32 + (wid & 1) * 16 + col;
  const unsigned short* xb = xTb + (size_t)b * 262144;
  int h0 = n0c >> 8, w0 = (n0c >> 4) & 15, dd0 = n0c & 15;
  f32x4 acc[2];
  acc[0] = zero4();
  acc[1] = zero4();
#pragma unroll
  for (int k = 0; k < 27; k++) {
    const int dh = k / 9 - 1;
    const int dw = (k / 3) % 3 - 1;
    const int dz = k % 3 - 1;
    bool v0 = ((unsigned)(h0 + dh) < 16u) & ((unsigned)(w0 + dw) < 16u) & ((unsigned)(dd0 + dz) < 16u);
    int np0 = v0 ? (n0c + dh * 256 + dw * 16 + dz) : n0c;
#pragma unroll
    for (int kc = 0; kc < 2; kc++) {
      bf16x8 av = *(const bf16x8*)(wkB + ((size_t)(k * 64 + co0 + col) * 64 + kc * 32 + kg * 8));
      bf16x8 bv = *(const bf16x8*)(xb + (size_t)np0 * 64 + kc * 32 + kg * 8);
      if (!v0) bv = (bf16x8){0, 0, 0, 0, 0, 0, 0, 0};
      acc[kc] = MFMA16(av, bv, acc[kc]);
    }
  }
#pragma unroll
  for (int r = 0; r < 4; r++) {
    int co = co0 + kg * 4 + r;
    botS[(size_t)(b * 64 + co) * 4096 + n0c] = f2bf(acc[0][r] + acc[1][r] + bbias[co]);
  }
}

// ---------------- out 3x3x3 conv -> f32 d_out ----------------
__global__ void k_convOut(const unsigned short* __restrict__ wk,
                          const unsigned short* __restrict__ xTb,
                          const float* __restrict__ bias,
                          float* __restrict__ outF) {
  int bx = blockIdx.x;
  int b = bx >> 8;
  int rest = bx & 255;
  int nt = rest >> 1, ch = rest & 1;
  int t = threadIdx.x;
  int lane = t & 63, wid = t >> 6;
  int col = lane & 15, kg = lane >> 4;
  int co0 = ch * 32 + (wid >> 1) * 16;
  int n0c = nt * 32 + (wid & 1) * 16 + col;
  const unsigned short* xb = xTb + (size_t)b * 262144;
  int h0 = n0c >> 8, w0 = (n0c >> 4) & 15, dd0 = n0c & 15;
  f32x4 acc[2];
  acc[0] = zero4();
  acc[1] = zero4();
#pragma unroll
  for (int k = 0; k < 27; k++) {
    const int dh = k / 9 - 1;
    const int dw = (k / 3) % 3 - 1;
    const int dz = k % 3 - 1;
    bool v0 = ((unsigned)(h0 + dh) < 16u) & ((unsigned)(w0 + dw) < 16u) & ((unsigned)(dd0 + dz) < 16u);
    int np0 = v0 ? (n0c + dh * 256 + dw * 16 + dz) : n0c;
#pragma unroll
    for (int kc = 0; kc < 2; kc++) {
      bf16x8 av = *(const bf16x8*)(wk + ((size_t)(k * 64 + co0 + col) * 64 + kc * 32 + kg * 8));
      bf16x8 bv = *(const bf16x8*)(xb + (size_t)np0 * 64 + kc * 32 + kg * 8);
      if (!v0) bv = (bf16x8){0, 0, 0, 0, 0, 0, 0, 0};
      acc[kc] = MFMA16(av, bv, acc[kc]);
    }
  }
#pragma unroll
  for (int r = 0; r < 4; r++) {
    int co = co0 + kg * 4 + r;
    outF[(size_t)(b * 64 + co) * 4096 + n0c] = acc[0][r] + acc[1][r] + bias[co];
  }
}

// ---------------- pass 2: P=exp2(S'), O-partials + Z-partials ----------------
// grid = B x 32 ntpairs(128 rows) x 8 mchunks(512 m); wave w owns rows {+w*16, +64+w*16}.
__global__ __launch_bounds__(256, 2) void k_pass2(
    const unsigned short* __restrict__ cenT, const unsigned short* __restrict__ topT,
    const unsigned short* __restrict__ botS,
    unsigned short* __restrict__ part, float* __restrict__ Zpart) {
  __shared__ __align__(16) unsigned short topS[2][4096];
  __shared__ __align__(16) unsigned short botL[2][4096];
  __shared__ __align__(16) unsigned short pT[4][2][1024];
  __shared__ float zred[4];
  int bx = blockIdx.x;
  int b = bx >> 8;
  int ntp = (bx >> 3) & 31;
  int mc = bx & 7;
  int t = threadIdx.x;
  int lane = t & 63, w = t >> 6;
  int col = lane & 15, kg = lane >> 4;
  const unsigned short* cb = cenT + (size_t)b * 262144;
  const unsigned short* tb = topT + (size_t)b * 262144;
  const unsigned short* bb = botS + (size_t)b * 262144;
  int nA = ntp * 128 + w * 16;
  int mcBase = mc * 512;
  int row8 = lane >> 3, blk = lane & 7;
  int sw = blk ^ (row8 & 7);

  bf16x8 aA0 = *(const bf16x8*)(cb + (size_t)(nA + col) * 64 + kg * 8);
  bf16x8 aA1 = *(const bf16x8*)(cb + (size_t)(nA + col) * 64 + 32 + kg * 8);
  bf16x8 aB0 = *(const bf16x8*)(cb + (size_t)(nA + 64 + col) * 64 + kg * 8);
  bf16x8 aB1 = *(const bf16x8*)(cb + (size_t)(nA + 64 + col) * 64 + 32 + kg * 8);

  // prologue stage j=0: waves 0,1 -> top; waves 2,3 -> bot
  if (w < 2) {
#pragma unroll
    for (int q = 0; q < 4; q++) {
      int s = w * 4 + q;
      gll16(tb + (size_t)(mcBase + s * 8 + row8) * 64 + sw * 8, &topS[0][s * 512]);
    }
  } else {
#pragma unroll
    for (int q = 0; q < 4; q++) {
      int s = (w - 2) * 4 + q;
      gll16(bb + (size_t)(s * 8 + row8) * 4096 + mcBase + sw * 8, &botL[0][s * 512]);
    }
  }
  __syncthreads();

  f32x4 accOA[4], accOB[4];
#pragma unroll
  for (int ct = 0; ct < 4; ct++) {
    accOA[ct] = zero4();
    accOB[ct] = zero4();
  }
  float zs = 0.f;
  int swc = (col & 7) << 3;
  unsigned short* pw0 = &pT[w][0][0];
  unsigned short* pw1 = &pT[w][1][0];

  for (int j = 0; j < 8; j++) {
    int cur = j & 1;
    if (j < 7) {
      int m0n = mcBase + (j + 1) * 64;
      if (w < 2) {
#pragma unroll
        for (int q = 0; q < 4; q++) {
          int s = w * 4 + q;
          gll16(tb + (size_t)(m0n + s * 8 + row8) * 64 + sw * 8, &topS[cur ^ 1][s * 512]);
        }
      } else {
#pragma unroll
        for (int q = 0; q < 4; q++) {
          int s = (w - 2) * 4 + q;
          gll16(bb + (size_t)(s * 8 + row8) * 4096 + m0n + sw * 8, &botL[cur ^ 1][s * 512]);
        }
      }
    }
    // S tiles (16n x 64m) for both row-groups; top B-frags register-shared
    f32x4 sA[4], sB[4];
#pragma unroll
    for (int mt = 0; mt < 4; mt++) {
      bf16x8 b0 = *(const bf16x8*)&topS[cur][(mt * 16 + col) * 64 + ((kg * 8) ^ swc)];
      bf16x8 b1 = *(const bf16x8*)&topS[cur][(mt * 16 + col) * 64 + ((32 + kg * 8) ^ swc)];
      sA[mt] = MFMA16(aA1, b1, MFMA16(aA0, b0, zero4()));
      sB[mt] = MFMA16(aB1, b1, MFMA16(aB0, b0, zero4()));
    }
    // P = exp2(S') -> per-wave LDS tiles (D-layout -> A-layout transpose), Z accumulate
#pragma unroll
    for (int mt = 0; mt < 4; mt++)
#pragma unroll
      for (int r = 0; r < 4; r++) {
        int nrow = kg * 4 + r;
        int msw = (mt * 16 + col) ^ ((nrow & 7) << 3);
        float eA = fexp2(sA[mt][r]);
        float eB = fexp2(sB[mt][r]);
        zs += eA + eB;
        pw0[nrow * 64 + msw] = f2bf(eA);
        pw1[nrow * 64 + msw] = f2bf(eB);
      }
    // PV for both tiles; bot B-frags register-shared
#pragma unroll
    for (int kc = 0; kc < 2; kc++) {
      bf16x8 paA = *(const bf16x8*)&pw0[col * 64 + ((kc * 32 + kg * 8) ^ swc)];
      bf16x8 paB = *(const bf16x8*)&pw1[col * 64 + ((kc * 32 + kg * 8) ^ swc)];
#pragma unroll
      for (int ct = 0; ct < 4; ct++) {
        bf16x8 bv = *(const bf16x8*)&botL[cur][(ct * 16 + col) * 64 + ((kc * 32 + kg * 8) ^ swc)];
        accOA[ct] = MFMA16(paA, bv, accOA[ct]);
        accOB[ct] = MFMA16(paB, bv, accOB[ct]);
      }
    }
    __syncthreads();
  }
  // raw bf16 partials: part[b][mc][n][c]  (invZ applied in k_xt1)
  unsigned short* po = part + (((size_t)(b * 8 + mc) * 4096 + nA) << 6);
#pragma unroll
  for (int ct = 0; ct < 4; ct++)
#pragma unroll
    for (int r = 0; r < 4; r++) {
      po[(kg * 4 + r) * 64 + ct * 16 + col] = f2bf(accOA[ct][r]);
      po[(64 + kg * 4 + r) * 64 + ct * 16 + col] = f2bf(accOB[ct][r]);  // tile B: rows nA+64..+79
    }
  // Z partial: wave reduce + block reduce
#pragma unroll
  for (int off = 32; off; off >>= 1) zs += __shfl_xor(zs, off);
  if (lane == 0) zred[w] = zs;
  __syncthreads();
  if (t == 0) Zpart[b * 256 + ntp * 8 + mc] = zred[0] + zred[1] + zred[2] + zred[3];
}

// ---------------- yT = bf16(x + (sum_mc part) * invZ), with Z reduce prologue ----------------
__global__ void k_xt1(const float* __restrict__ x, const unsigned short* __restrict__ part,
                      const float* __restrict__ Zpart, unsigned short* __restrict__ xT) {
  __shared__ float tile[64][65];
  __shared__ float zr[4];
  int bx = blockIdx.x;
  int b = bx >> 6;
  int n0 = (bx & 63) << 6;
  int t = threadIdx.x;
  // Z reduce (256 partials per batch)
  float zv = Zpart[b * 256 + t];
#pragma unroll
  for (int off = 32; off; off >>= 1) zv += __shfl_xor(zv, off);
  if ((t & 63) == 0) zr[t >> 6] = zv;
  __syncthreads();
  float invZ = 1.0f / (zr[0] + zr[1] + zr[2] + zr[3]);
  {
    int nl = t & 63, cq = t >> 6;
    const float* xb = x + (size_t)b * 262144;
    int nt6 = n0 >> 6;
#pragma unroll
    for (int j = 0; j < 16; j++) {
      int c = cq * 16 + j;
      float v = xb[(size_t)c * 4096 + n0 + nl];
      // sp flat [b][nA][cA]; nA = c*64 + nt6 (fixed per j), cA = nl (coalesced)
      float s = 0.f;
#pragma unroll
      for (int mcq = 0; mcq < 8; mcq++)
        s += bf2f(part[(((size_t)(b * 8 + mcq) * 4096) + c * 64 + nt6) * 64 + nl]);
      tile[c][nl] = v + s * invZ;
    }
  }
  __syncthreads();
  {
    int n = t >> 2, c0 = (t & 3) << 4;
    bf16x8 o0, o1;
#pragma unroll
    for (int j = 0; j < 8; j++) {
      o0[j] = (short)f2bf(tile[c0 + j][n]);
      o1[j] = (short)f2bf(tile[c0 + 8 + j][n]);
    }
    unsigned short* dst = xT + ((size_t)(b * 4096 + n0 + n)) * 64 + c0;
    *(bf16x8*)(dst) = o0;
    *(bf16x8*)(dst + 8) = o1;
  }
}

// ---------------- host ----------------
extern "C" void kernel_launch(void* const* d_in, const int* in_sizes, int n_in,
                              void* d_out, int out_size, void* d_ws, size_t ws_size,
                              hipStream_t stream) {
  const float* x = (const float*)d_in[0];
  const float* tw = (const float*)d_in[1];
  const float* tb = (const float*)d_in[2];
  const float* cw = (const float*)d_in[3];
  const float* cbb = (const float*)d_in[4];
  const float* bw = (const float*)d_in[5];
  const float* bb = (const float*)d_in[6];
  const float* ow = (const float*)d_in[7];
  const float* ob = (const float*)d_in[8];
  float* out = (float*)d_out;
  char* ws = (char*)d_ws;

  unsigned short* wkTop = (unsigned short*)(ws + 0);        // 8 KB
  unsigned short* wkCen = (unsigned short*)(ws + 8192);     // 8 KB
  unsigned short* wkBot = (unsigned short*)(ws + 16384);    // 216 KB
  unsigned short* wkOut = (unsigned short*)(ws + 237568);   // 216 KB
  unsigned short* xT = (unsigned short*)(ws + 458752);      // 1 MB
  unsigned short* topT = (unsigned short*)(ws + 1507328);   // 1 MB
  unsigned short* cenT = (unsigned short*)(ws + 2555904);   // 1 MB
  unsigned short* botS = (unsigned short*)(ws + 3604480);   // 1 MB
  unsigned short* yT = (unsigned short*)(ws + 4653056);     // 1 MB
  unsigned short* part = (unsigned short*)(ws + 5701632);   // 8 MB bf16 [2][8][4096][64]
  float* Zpart = (float*)(ws + 14090240);                   // 2 KB

  k_prep<<<560, 256, 0, stream>>>(tw, cw, bw, ow, x, wkTop, wkCen, wkBot, wkOut, xT);
  k_convA<<<1024, 256, 0, stream>>>(wkTop, wkCen, wkBot, xT, tb, cbb, bb, topT, cenT, botS);
  k_pass2<<<512, 256, 0, stream>>>(cenT, topT, botS, part, Zpart);
  k_xt1<<<128, 256, 0, stream>>>(x, part, Zpart, yT);
  k_convOut<<<512, 256, 0, stream>>>(wkOut, yT, ob, out);
}

// Round 8
// 46.696 us; speedup vs baseline: 3.7795x; 1.8459x over previous
//
#include <hip/hip_runtime.h>

// PAB3D on MI355X (gfx950).  B=2, C=P=64, H=W=D=16, N=4096.
// R8: 27-tap convs rebuilt with LDS halo staging (24KB, XOR-swizzled via
// pre-swizzled gll16 source) + pre-permuted coalesced weight fragments.
// Kills the 16-line B-frag/A-frag gathers (same disease R4 cured in pass1/2).
// pass2 / xt1 unchanged from R7.

typedef __attribute__((ext_vector_type(8))) short bf16x8;
typedef __attribute__((ext_vector_type(4))) short short4v;
typedef __attribute__((ext_vector_type(4))) float f32x4;

#define DEVI static __device__ __forceinline__

DEVI f32x4 MFMA16(bf16x8 a, bf16x8 b, f32x4 c) {
  return __builtin_amdgcn_mfma_f32_16x16x32_bf16(a, b, c, 0, 0, 0);
}
DEVI f32x4 zero4() { return (f32x4){0.f, 0.f, 0.f, 0.f}; }

DEVI unsigned short f2bf(float f) {  // RNE float->bf16
  unsigned u = __float_as_uint(f);
  return (unsigned short)((u + 0x7fffu + ((u >> 16) & 1u)) >> 16);
}
DEVI float bf2f(unsigned short u) { return __uint_as_float((unsigned)u << 16); }
DEVI float fexp2(float x) { return __builtin_amdgcn_exp2f(x); }

// async global->LDS, 16B per lane; lds dest is wave-uniform base (HW adds lane*16)
DEVI void gll16(const unsigned short* g, unsigned short* l) {
  __builtin_amdgcn_global_load_lds(
      (const __attribute__((address_space(1))) void*)g,
      (__attribute__((address_space(3))) void*)l, 16, 0, 0);
}

// ---------------- fused: weight prep/permute (bx<432) + x transpose (bx>=432) --------
// Weight frag layout (A-operand, coalesced): [cog4][k][kc2][lane64][e8],
// holds w[co = cog*16 + (lane&15)][ci = kc*32 + (lane>>4)*8 + e].
__global__ void k_prep(const float* __restrict__ tw, const float* __restrict__ cw,
                       const float* __restrict__ bw, const float* __restrict__ ow,
                       const float* __restrict__ x,
                       unsigned short* __restrict__ wkTopF, unsigned short* __restrict__ wkCenF,
                       unsigned short* __restrict__ wkBotF, unsigned short* __restrict__ wkOutF,
                       unsigned short* __restrict__ xT, unsigned short* __restrict__ zbuf) {
  __shared__ float tile[64][65];
  int bx = blockIdx.x;
  int tid = threadIdx.x;
  if (bx == 0 && tid < 64) zbuf[tid] = 0;  // 128B zero region for OOB halo staging
  if (bx < 432) {
    int t = bx * 256 + tid;
    if (t < 4096) {  // 1x1 weights: t = co*64+ci
      int co = t >> 6, ci = t & 63;
      int cog = co >> 4, col = co & 15, kc = ci >> 5, kg = (ci & 31) >> 3, e = ci & 7;
      int dst = (((cog * 2 + kc) * 64) + col + 16 * kg) * 8 + e;
      wkTopF[dst] = f2bf(tw[t]);
      wkCenF[dst] = f2bf(cw[t]);
    }
    // 3x3x3 weights: src [co][ci][k27]
    int k = t % 27;
    int ci = (t / 27) & 63;
    int co = t / (27 * 64);
    int cog = co >> 4, col = co & 15, kc = ci >> 5, kg = (ci & 31) >> 3, e = ci & 7;
    int dst = ((((cog * 27 + k) * 2 + kc) * 64) + col + 16 * kg) * 8 + e;
    wkBotF[dst] = f2bf(bw[t]);
    wkOutF[dst] = f2bf(ow[t]);
    return;
  }
  int bx2 = bx - 432;
  int b = bx2 >> 6;
  int n0 = (bx2 & 63) << 6;
  {
    int nl = tid & 63, cq = tid >> 6;
    const float* xb = x + (size_t)b * 262144;
#pragma unroll
    for (int j = 0; j < 16; j++) {
      int c = cq * 16 + j;
      tile[c][nl] = xb[(size_t)c * 4096 + n0 + nl];
    }
  }
  __syncthreads();
  {
    int n = tid >> 2, c0 = (tid & 3) << 4;
    bf16x8 o0, o1;
#pragma unroll
    for (int j = 0; j < 8; j++) {
      o0[j] = (short)f2bf(tile[c0 + j][n]);
      o1[j] = (short)f2bf(tile[c0 + 8 + j][n]);
    }
    unsigned short* dst = xT + ((size_t)(b * 4096 + n0 + n)) * 64 + c0;
    *(bf16x8*)(dst) = o0;
    *(bf16x8*)(dst + 8) = o1;
  }
}

// ---------------- staged 27-tap conv body ----------------
// block: b(2) x h(16) x wp(8 w-pairs) x ch(2 co-halves); 32n x 32co out.
// Halo 3h x 4w x 16d voxels (192 x 128B = 24KB) staged XOR-swizzled.
template <int OMODE>  // 2: bf16 [co][n]; 1: f32 [co][n]
DEVI void conv3_body(int bx, int t,
                     const unsigned short* __restrict__ wkF,
                     const unsigned short* __restrict__ xTb,
                     const float* __restrict__ bias,
                     const unsigned short* __restrict__ zbuf,
                     float* __restrict__ outF, unsigned short* __restrict__ outH,
                     unsigned short* hl) {
  int ch = bx & 1, wp = (bx >> 1) & 7, h = (bx >> 4) & 15, b = bx >> 8;
  int lane = t & 63, w = t >> 6;
  int col = lane & 15, kg = lane >> 4;
  const unsigned short* xb = xTb + (size_t)b * 262144;
  // stage halo: wave w -> voxels [48w, 48w+48), 6 issues x 8 voxels
  int row8 = lane >> 3, blk = lane & 7;
#pragma unroll
  for (int q = 0; q < 6; q++) {
    int vi0 = w * 48 + q * 8;
    int vi = vi0 + row8;
    int dhv = vi >> 6, wv = (vi >> 4) & 3, dv = vi & 15;
    int hh = h + dhv - 1, ww = wp * 2 + wv - 1;
    bool val = ((unsigned)hh < 16u) & ((unsigned)ww < 16u);
    int sw = blk ^ (vi & 7);
    const unsigned short* src =
        val ? (xb + ((size_t)((hh * 256 + ww * 16 + dv)) << 6) + sw * 8) : (zbuf + blk * 8);
    gll16(src, hl + vi0 * 64);
  }
  __syncthreads();
  int wi = w >> 1;            // which w of the pair
  int cg = ch * 2 + (w & 1);  // co-group (16 co)
  const char* hlb = (const char*)hl;
  f32x4 acc0 = zero4(), acc1 = zero4();
#pragma unroll
  for (int k = 0; k < 27; k++) {
    const int dh = k / 9;            // 0..2 (slot index, = dh'+1)
    const int dw = (k / 3) % 3;      // 0..2
    const int dz = k % 3 - 1;        // -1..1
    int dsum = col + dz;
    bool vd = (unsigned)dsum < 16u;
    int dcl = vd ? dsum : col;       // clamped in-range index (zeroed below)
    int sv = dh * 64 + (wi + dw) * 16 + dcl;
    const unsigned short* wfk = wkF + (((size_t)(cg * 27 + k)) << 10) + lane * 8;
#pragma unroll
    for (int kc = 0; kc < 2; kc++) {
      bf16x8 av = *(const bf16x8*)(wfk + (kc << 9));
      int g = (kc * 4 + kg) ^ (sv & 7);
      bf16x8 bv = *(const bf16x8*)(hlb + sv * 128 + g * 16);
      if (!vd) bv = (bf16x8){0, 0, 0, 0, 0, 0, 0, 0};
      if (kc == 0) acc0 = MFMA16(av, bv, acc0);
      else acc1 = MFMA16(av, bv, acc1);
    }
  }
  int n0c = h * 256 + (wp * 2 + wi) * 16 + col;
#pragma unroll
  for (int r = 0; r < 4; r++) {
    int co = ch * 32 + (w & 1) * 16 + kg * 4 + r;
    float v = acc0[r] + acc1[r] + bias[co];
    if (OMODE == 2)
      outH[(size_t)(b * 64 + co) * 4096 + n0c] = f2bf(v);
    else
      outF[(size_t)(b * 64 + co) * 4096 + n0c] = v;
  }
}

// ---------------- fused: top+center 1x1x1 (bx<512) + bottom 3x3x3 staged (bx>=512) ----
__global__ __launch_bounds__(256, 2) void k_convA(
    const unsigned short* __restrict__ wkTf, const unsigned short* __restrict__ wkCf,
    const unsigned short* __restrict__ wkBf, const unsigned short* __restrict__ xTb,
    const float* __restrict__ tbias, const float* __restrict__ cbias,
    const float* __restrict__ bbias, const unsigned short* __restrict__ zbuf,
    unsigned short* __restrict__ topT, unsigned short* __restrict__ cenT,
    unsigned short* __restrict__ botS) {
  __shared__ __align__(16) unsigned short hl[192 * 64];
  int bx0 = blockIdx.x;
  int t = threadIdx.x;
  if (bx0 >= 512) {
    conv3_body<2>(bx0 - 512, t, wkBf, xTb, bbias, zbuf, nullptr, botS, hl);
    return;
  }
  int lane = t & 63, wid = t >> 6;
  int col = lane & 15, kg = lane >> 4;
  int bx = bx0;
  int b = bx >> 8;
  int rest = bx & 255;
  int nt = rest >> 1, ch = rest & 1;
  int cg = ch * 2 + (wid >> 1);
  int co0 = ch * 32 + (wid >> 1) * 16;
  int n0c = nt * 32 + (wid & 1) * 16 + col;
  const unsigned short* xb = xTb + (size_t)b * 262144;
  f32x4 aT0 = zero4(), aT1 = zero4(), aC0 = zero4(), aC1 = zero4();
#pragma unroll
  for (int kc = 0; kc < 2; kc++) {
    bf16x8 bv = *(const bf16x8*)(xb + (size_t)n0c * 64 + kc * 32 + kg * 8);
    bf16x8 avT = *(const bf16x8*)(wkTf + (((size_t)cg * 2 + kc) * 64 + lane) * 8);
    bf16x8 avC = *(const bf16x8*)(wkCf + (((size_t)cg * 2 + kc) * 64 + lane) * 8);
    if (kc == 0) {
      aT0 = MFMA16(avT, bv, aT0);
      aC0 = MFMA16(avC, bv, aC0);
    } else {
      aT1 = MFMA16(avT, bv, aT1);
      aC1 = MFMA16(avC, bv, aC1);
    }
  }
  const float LOG2E = 1.4426950408889634f;
  short4v sT, sC;
#pragma unroll
  for (int r = 0; r < 4; r++) {
    float bvT = tbias[co0 + kg * 4 + r];
    float bvC = cbias[co0 + kg * 4 + r];
    sT[r] = (short)f2bf(aT0[r] + aT1[r] + bvT);
    sC[r] = (short)f2bf((aC0[r] + aC1[r] + bvC) * LOG2E);  // fold log2e for exp2
  }
  size_t o = (size_t)(b * 4096 + n0c) * 64 + co0 + kg * 4;
  *(short4v*)(topT + o) = sT;
  *(short4v*)(cenT + o) = sC;
}

// ---------------- out 3x3x3 conv (staged) -> f32 d_out ----------------
__global__ __launch_bounds__(256, 2) void k_convOut(
    const unsigned short* __restrict__ wkOf, const unsigned short* __restrict__ xTb,
    const float* __restrict__ bias, const unsigned short* __restrict__ zbuf,
    float* __restrict__ outF) {
  __shared__ __align__(16) unsigned short hl[192 * 64];
  conv3_body<1>(blockIdx.x, threadIdx.x, wkOf, xTb, bias, zbuf, outF, nullptr, hl);
}

// ---------------- pass 2: P=exp2(S'), O-partials + Z-partials ----------------
// grid = B x 32 ntpairs(128 rows) x 8 mchunks(512 m); wave w owns rows {+w*16, +64+w*16}.
__global__ __launch_bounds__(256, 2) void k_pass2(
    const unsigned short* __restrict__ cenT, const unsigned short* __restrict__ topT,
    const unsigned short* __restrict__ botS,
    unsigned short* __restrict__ part, float* __restrict__ Zpart) {
  __shared__ __align__(16) unsigned short topS[2][4096];
  __shared__ __align__(16) unsigned short botL[2][4096];
  __shared__ __align__(16) unsigned short pT[4][2][1024];
  __shared__ float zred[4];
  int bx = blockIdx.x;
  int b = bx >> 8;
  int ntp = (bx >> 3) & 31;
  int mc = bx & 7;
  int t = threadIdx.x;
  int lane = t & 63, w = t >> 6;
  int col = lane & 15, kg = lane >> 4;
  const unsigned short* cb = cenT + (size_t)b * 262144;
  const unsigned short* tb = topT + (size_t)b * 262144;
  const unsigned short* bb = botS + (size_t)b * 262144;
  int nA = ntp * 128 + w * 16;
  int mcBase = mc * 512;
  int row8 = lane >> 3, blk = lane & 7;
  int sw = blk ^ (row8 & 7);

  bf16x8 aA0 = *(const bf16x8*)(cb + (size_t)(nA + col) * 64 + kg * 8);
  bf16x8 aA1 = *(const bf16x8*)(cb + (size_t)(nA + col) * 64 + 32 + kg * 8);
  bf16x8 aB0 = *(const bf16x8*)(cb + (size_t)(nA + 64 + col) * 64 + kg * 8);
  bf16x8 aB1 = *(const bf16x8*)(cb + (size_t)(nA + 64 + col) * 64 + 32 + kg * 8);

  // prologue stage j=0: waves 0,1 -> top; waves 2,3 -> bot
  if (w < 2) {
#pragma unroll
    for (int q = 0; q < 4; q++) {
      int s = w * 4 + q;
      gll16(tb + (size_t)(mcBase + s * 8 + row8) * 64 + sw * 8, &topS[0][s * 512]);
    }
  } else {
#pragma unroll
    for (int q = 0; q < 4; q++) {
      int s = (w - 2) * 4 + q;
      gll16(bb + (size_t)(s * 8 + row8) * 4096 + mcBase + sw * 8, &botL[0][s * 512]);
    }
  }
  __syncthreads();

  f32x4 accOA[4], accOB[4];
#pragma unroll
  for (int ct = 0; ct < 4; ct++) {
    accOA[ct] = zero4();
    accOB[ct] = zero4();
  }
  float zs = 0.f;
  int swc = (col & 7) << 3;
  unsigned short* pw0 = &pT[w][0][0];
  unsigned short* pw1 = &pT[w][1][0];

  for (int j = 0; j < 8; j++) {
    int cur = j & 1;
    if (j < 7) {
      int m0n = mcBase + (j + 1) * 64;
      if (w < 2) {
#pragma unroll
        for (int q = 0; q < 4; q++) {
          int s = w * 4 + q;
          gll16(tb + (size_t)(m0n + s * 8 + row8) * 64 + sw * 8, &topS[cur ^ 1][s * 512]);
        }
      } else {
#pragma unroll
        for (int q = 0; q < 4; q++) {
          int s = (w - 2) * 4 + q;
          gll16(bb + (size_t)(s * 8 + row8) * 4096 + m0n + sw * 8, &botL[cur ^ 1][s * 512]);
        }
      }
    }
    // S tiles (16n x 64m) for both row-groups; top B-frags register-shared
    f32x4 sA[4], sB[4];
#pragma unroll
    for (int mt = 0; mt < 4; mt++) {
      bf16x8 b0 = *(const bf16x8*)&topS[cur][(mt * 16 + col) * 64 + ((kg * 8) ^ swc)];
      bf16x8 b1 = *(const bf16x8*)&topS[cur][(mt * 16 + col) * 64 + ((32 + kg * 8) ^ swc)];
      sA[mt] = MFMA16(aA1, b1, MFMA16(aA0, b0, zero4()));
      sB[mt] = MFMA16(aB1, b1, MFMA16(aB0, b0, zero4()));
    }
    // P = exp2(S') -> per-wave LDS tiles (D-layout -> A-layout transpose), Z accumulate
#pragma unroll
    for (int mt = 0; mt < 4; mt++)
#pragma unroll
      for (int r = 0; r < 4; r++) {
        int nrow = kg * 4 + r;
        int msw = (mt * 16 + col) ^ ((nrow & 7) << 3);
        float eA = fexp2(sA[mt][r]);
        float eB = fexp2(sB[mt][r]);
        zs += eA + eB;
        pw0[nrow * 64 + msw] = f2bf(eA);
        pw1[nrow * 64 + msw] = f2bf(eB);
      }
    // PV for both tiles; bot B-frags register-shared
#pragma unroll
    for (int kc = 0; kc < 2; kc++) {
      bf16x8 paA = *(const bf16x8*)&pw0[col * 64 + ((kc * 32 + kg * 8) ^ swc)];
      bf16x8 paB = *(const bf16x8*)&pw1[col * 64 + ((kc * 32 + kg * 8) ^ swc)];
#pragma unroll
      for (int ct = 0; ct < 4; ct++) {
        bf16x8 bv = *(const bf16x8*)&botL[cur][(ct * 16 + col) * 64 + ((kc * 32 + kg * 8) ^ swc)];
        accOA[ct] = MFMA16(paA, bv, accOA[ct]);
        accOB[ct] = MFMA16(paB, bv, accOB[ct]);
      }
    }
    __syncthreads();
  }
  // raw bf16 partials: part[b][mc][n][c]  (invZ applied in k_xt1)
  unsigned short* po = part + (((size_t)(b * 8 + mc) * 4096 + nA) << 6);
#pragma unroll
  for (int ct = 0; ct < 4; ct++)
#pragma unroll
    for (int r = 0; r < 4; r++) {
      po[(kg * 4 + r) * 64 + ct * 16 + col] = f2bf(accOA[ct][r]);
      po[(64 + kg * 4 + r) * 64 + ct * 16 + col] = f2bf(accOB[ct][r]);
    }
  // Z partial: wave reduce + block reduce
#pragma unroll
  for (int off = 32; off; off >>= 1) zs += __shfl_xor(zs, off);
  if (lane == 0) zred[w] = zs;
  __syncthreads();
  if (t == 0) Zpart[b * 256 + ntp * 8 + mc] = zred[0] + zred[1] + zred[2] + zred[3];
}

// ---------------- yT = bf16(x + (sum_mc part) * invZ), with Z reduce prologue --------
__global__ void k_xt1(const float* __restrict__ x, const unsigned short* __restrict__ part,
                      const float* __restrict__ Zpart, unsigned short* __restrict__ xT) {
  __shared__ float tile[64][65];
  __shared__ float zr[4];
  int bx = blockIdx.x;
  int b = bx >> 6;
  int n0 = (bx & 63) << 6;
  int t = threadIdx.x;
  float zv = Zpart[b * 256 + t];
#pragma unroll
  for (int off = 32; off; off >>= 1) zv += __shfl_xor(zv, off);
  if ((t & 63) == 0) zr[t >> 6] = zv;
  __syncthreads();
  float invZ = 1.0f / (zr[0] + zr[1] + zr[2] + zr[3]);
  {
    int nl = t & 63, cq = t >> 6;
    const float* xb = x + (size_t)b * 262144;
    int nt6 = n0 >> 6;
#pragma unroll
    for (int j = 0; j < 16; j++) {
      int c = cq * 16 + j;
      float v = xb[(size_t)c * 4096 + n0 + nl];
      float s = 0.f;
#pragma unroll
      for (int mcq = 0; mcq < 8; mcq++)
        s += bf2f(part[(((size_t)(b * 8 + mcq) * 4096) + c * 64 + nt6) * 64 + nl]);
      tile[c][nl] = v + s * invZ;
    }
  }
  __syncthreads();
  {
    int n = t >> 2, c0 = (t & 3) << 4;
    bf16x8 o0, o1;
#pragma unroll
    for (int j = 0; j < 8; j++) {
      o0[j] = (short)f2bf(tile[c0 + j][n]);
      o1[j] = (short)f2bf(tile[c0 + 8 + j][n]);
    }
    unsigned short* dst = xT + ((size_t)(b * 4096 + n0 + n)) * 64 + c0;
    *(bf16x8*)(dst) = o0;
    *(bf16x8*)(dst + 8) = o1;
  }
}

// ---------------- host ----------------
extern "C" void kernel_launch(void* const* d_in, const int* in_sizes, int n_in,
                              void* d_out, int out_size, void* d_ws, size_t ws_size,
                              hipStream_t stream) {
  const float* x = (const float*)d_in[0];
  const float* tw = (const float*)d_in[1];
  const float* tb = (const float*)d_in[2];
  const float* cw = (const float*)d_in[3];
  const float* cbb = (const float*)d_in[4];
  const float* bw = (const float*)d_in[5];
  const float* bb = (const float*)d_in[6];
  const float* ow = (const float*)d_in[7];
  const float* ob = (const float*)d_in[8];
  float* out = (float*)d_out;
  char* ws = (char*)d_ws;

  unsigned short* wkTopF = (unsigned short*)(ws + 0);       // 8 KB (frag layout)
  unsigned short* wkCenF = (unsigned short*)(ws + 8192);    // 8 KB
  unsigned short* wkBotF = (unsigned short*)(ws + 16384);   // 216 KB
  unsigned short* wkOutF = (unsigned short*)(ws + 237568);  // 216 KB
  unsigned short* xT = (unsigned short*)(ws + 458752);      // 1 MB
  unsigned short* topT = (unsigned short*)(ws + 1507328);   // 1 MB
  unsigned short* cenT = (unsigned short*)(ws + 2555904);   // 1 MB
  unsigned short* botS = (unsigned short*)(ws + 3604480);   // 1 MB
  unsigned short* yT = (unsigned short*)(ws + 4653056);     // 1 MB
  unsigned short* part = (unsigned short*)(ws + 5701632);   // 8 MB bf16 [2][8][4096][64]
  float* Zpart = (float*)(ws + 14090240);                   // 2 KB
  unsigned short* zbuf = (unsigned short*)(ws + 14092288);  // 128 B zeros

  k_prep<<<560, 256, 0, stream>>>(tw, cw, bw, ow, x, wkTopF, wkCenF, wkBotF, wkOutF, xT, zbuf);
  k_convA<<<1024, 256, 0, stream>>>(wkTopF, wkCenF, wkBotF, xT, tb, cbb, bb, zbuf, topT, cenT, botS);
  k_pass2<<<512, 256, 0, stream>>>(cenT, topT, botS, part, Zpart);
  k_xt1<<<128, 256, 0, stream>>>(x, part, Zpart, yT);
  k_convOut<<<512, 256, 0, stream>>>(wkOutF, yT, ob, zbuf, out);
}